// Round 1
// baseline (252.351 us; speedup 1.0000x reference)
//
#include <hip/hip_runtime.h>

// Dims (fixed by the reference)
#define BB 4
#define HH 8
#define NN 1024
// K padded: 64 (ns) + 3 (coords) + 1 (bias) = 68 -> pad to 96 = 3 x 32
#define KP 96
#define LSTR 104   // LDS row stride in shorts (208 B = 16*13, bank-friendly)

typedef __attribute__((ext_vector_type(8))) short short8;
typedef __attribute__((ext_vector_type(4))) short short4v;
typedef __attribute__((ext_vector_type(4))) float f32x4;

__device__ __forceinline__ short f2bf(float f){
  unsigned u = __builtin_bit_cast(unsigned, f);
  u += 0x7FFFu + ((u >> 16) & 1u);       // RNE
  return (short)(u >> 16);
}

// ---------------- K1: per-head Gram panel ----------------
// PT[h][kk][c] = sum_d Wq[h*1024+d][c] * X[d][kk]
// X[d][kk] = Wk[.,kk] (kk<64) | Wlq[.,kk-64] (64..66) | blq (67) | 0 (pad)
__global__ __launch_bounds__(1024) void k_prep_pt(
    const float* __restrict__ Wq, const float* __restrict__ Wk,
    const float* __restrict__ Wlq, const float* __restrict__ blq,
    short* __restrict__ PT){
  int t = threadIdx.x, c = t & 63, p = t >> 6;          // p: 0..15 d-partitions
  int h = blockIdx.y, kk0 = blockIdx.x * 8;
  float acc[8];
  #pragma unroll
  for (int i = 0; i < 8; ++i) acc[i] = 0.f;
  for (int dd = 0; dd < 64; ++dd){
    int o = h * 1024 + p * 64 + dd;
    float wq = Wq[o * 64 + c];                           // coalesced over c
    #pragma unroll
    for (int i = 0; i < 8; ++i){
      int kk = kk0 + i;
      float bv;
      if (kk < 64)        bv = Wk[o * 64 + kk];
      else if (kk < 67)   bv = Wlq[o * 3 + (kk - 64)];
      else if (kk == 67)  bv = blq[o];
      else                bv = 0.f;
      acc[i] += wq * bv;
    }
  }
  __shared__ float red[16][64][8];
  #pragma unroll
  for (int i = 0; i < 8; ++i) red[p][c][i] = acc[i];
  __syncthreads();
  if (p == 0){
    #pragma unroll
    for (int i = 0; i < 8; ++i){
      float s = 0.f;
      for (int pp = 0; pp < 16; ++pp) s += red[pp][c][i];
      PT[(h * KP + kk0 + i) * 64 + c] = f2bf(s);
    }
  }
}

// ---------------- K2: B panel  Bmat[b][m][kk] (bf16) ----------------
// kk<64: ns[b][kk][m] (transposed), 64..66: coords[b][m][j], 67: 1, pad: 0
__global__ __launch_bounds__(256) void k_prep_b(
    const float* __restrict__ ns, const float* __restrict__ coord,
    short* __restrict__ Bm){
  int t = threadIdx.x;
  int b = blockIdx.y, m0 = blockIdx.x * 64;
  __shared__ float nsT[64][65];
  __shared__ float cst[3][64];
  #pragma unroll
  for (int it = 0; it < 16; ++it){
    int idx = it * 256 + t;
    int c = idx >> 6, mm = idx & 63;
    nsT[mm][c] = ns[(b * 64 + c) * NN + m0 + mm];        // coalesced over mm
  }
  if (t < 192){
    int j = t >> 6, mm = t & 63;
    cst[j][mm] = coord[(b * 3 + j) * NN + m0 + mm];
  }
  __syncthreads();
  #pragma unroll
  for (int it = 0; it < 24; ++it){
    int idx = it * 256 + t;                              // 64*96 = 6144
    int mm = idx / KP, kk = idx - mm * KP;
    float v = (kk < 64) ? nsT[mm][kk]
            : (kk < 67) ? cst[kk - 64][mm]
            : (kk == 67) ? 1.f : 0.f;
    Bm[(b * NN + m0 + mm) * KP + kk] = f2bf(v);
  }
}

// ---------------- K3: V panel  Vm[h*1024+d][kk] (bf16) ----------------
__global__ __launch_bounds__(256) void k_prep_v(
    const float* __restrict__ Wv, const float* __restrict__ Wlv,
    const float* __restrict__ blv, short* __restrict__ Vm){
  int t = threadIdx.x, o0 = blockIdx.x * 64;
  #pragma unroll
  for (int it = 0; it < 24; ++it){
    int idx = it * 256 + t;
    int r = idx / KP, kk = idx - r * KP;
    int o = o0 + r;
    float v = (kk < 64) ? Wv[o * 64 + kk]
            : (kk < 67) ? Wlv[o * 3 + (kk - 64)]
            : (kk == 67) ? blv[o] : 0.f;
    Vm[o * KP + kk] = f2bf(v);
  }
}

// ---------------- K4: fused attention ----------------
// Per WG: (b,h, 64-row n-block). Wave w owns rows n0+w*16..+15.
// A[n][kk] built in-kernel via MFMA from xs-tile and PT panel.
// Pass1: row sums of exp2(e*KEXP) over all m. Pass2: recompute e, vc GEMM,
// normalize, transposed float4 stores to out[b][h*1024+d][n].
__global__ __launch_bounds__(256) void attn_main(
    const float* __restrict__ xs, const short* __restrict__ PT,
    const short* __restrict__ Bmat, const short* __restrict__ Vm,
    float* __restrict__ out){
  __shared__ short xsL[64 * 64];        // bf16 [c][n_local]
  __shared__ short AL[64 * LSTR];       // bf16 A rows [n_local][kk]
  __shared__ short Bst[64 * LSTR];
  __shared__ short Vst[64 * LSTR];
  const int t = threadIdx.x, w = t >> 6, lane = t & 63;
  const int q = lane >> 4, ln = lane & 15;
  const int blk = blockIdx.x, nb = blk & 15, bh = blk >> 4;
  const int b = bh >> 3, h = bh & 7;
  const int n0 = nb * 64;

  // ---- stage xs[b][0..63][n0..n0+63] as bf16 ----
  const float* xsb = xs + b * 64 * NN;
  #pragma unroll
  for (int it = 0; it < 4; ++it){
    int idx = it * 256 + t;                     // 1024 float4 units
    int c = idx >> 4, nn4 = (idx & 15) << 2;
    f32x4 v = *(const f32x4*)(xsb + c * NN + n0 + nn4);
    short4v pk;
    #pragma unroll
    for (int j = 0; j < 4; ++j) pk[j] = f2bf(v[j]);
    *(short4v*)(&xsL[c * 64 + nn4]) = pk;
  }
  __syncthreads();

  // ---- build A tile rows for this wave via MFMA: A = xs^T . PT^T ----
  short8 xf0, xf1;
  #pragma unroll
  for (int j = 0; j < 8; ++j){
    xf0[j] = xsL[(q * 8 + j) * 64 + w * 16 + ln];
    xf1[j] = xsL[(32 + q * 8 + j) * 64 + w * 16 + ln];
  }
  const short* PTh = PT + h * KP * 64;
  #pragma unroll
  for (int kt = 0; kt < 6; ++kt){
    short8 p0 = *(const short8*)(PTh + (kt * 16 + ln) * 64 + q * 8);
    short8 p1 = *(const short8*)(PTh + (kt * 16 + ln) * 64 + 32 + q * 8);
    f32x4 a = {0.f, 0.f, 0.f, 0.f};
    a = __builtin_amdgcn_mfma_f32_16x16x32_bf16(xf0, p0, a, 0, 0, 0);
    a = __builtin_amdgcn_mfma_f32_16x16x32_bf16(xf1, p1, a, 0, 0, 0);
    #pragma unroll
    for (int r = 0; r < 4; ++r)
      AL[(w * 16 + q * 4 + r) * LSTR + kt * 16 + ln] = f2bf(a[r]);
  }
  __syncthreads();

  // ---- persistent fragments ----
  short8 af[3], bn[3];
  const short* Bb = Bmat + b * NN * KP;
  #pragma unroll
  for (int s = 0; s < 3; ++s){
    af[s] = *(const short8*)(&AL[(w * 16 + ln) * LSTR + s * 32 + q * 8]);
    bn[s] = *(const short8*)(Bb + (n0 + w * 16 + ln) * KP + s * 32 + q * 8);
  }
  const float KEXP = 0.045084220f;   // log2(e)/32  (SCALE = sqrt(1024) = 32)

  // ---- pass 1: row sums of exp ----
  float sum[4] = {0.f, 0.f, 0.f, 0.f};
  for (int mc = 0; mc < 16; ++mc){
    __syncthreads();
    #pragma unroll
    for (int it = 0; it < 3; ++it){
      int idx = it * 256 + t;                   // 768 uint4 units (12 KB)
      int row = idx / 12, seg = idx - row * 12;
      *(uint4*)(&Bst[row * LSTR + seg * 8]) =
          *(const uint4*)(Bb + (mc * 64 + row) * KP + seg * 8);
    }
    __syncthreads();
    #pragma unroll
    for (int sm = 0; sm < 4; ++sm){
      f32x4 e = {0.f, 0.f, 0.f, 0.f};
      #pragma unroll
      for (int s = 0; s < 3; ++s){
        short8 bf = *(const short8*)(&Bst[(sm * 16 + ln) * LSTR + s * 32 + q * 8]);
        e = __builtin_amdgcn_mfma_f32_16x16x32_bf16(af[s], bf, e, 0, 0, 0);
      }
      #pragma unroll
      for (int r = 0; r < 4; ++r) sum[r] += __builtin_amdgcn_exp2f(e[r] * KEXP);
    }
  }
  #pragma unroll
  for (int r = 0; r < 4; ++r){
    sum[r] += __shfl_xor(sum[r], 1);
    sum[r] += __shfl_xor(sum[r], 2);
    sum[r] += __shfl_xor(sum[r], 4);
    sum[r] += __shfl_xor(sum[r], 8);
  }
  float rinv[4];
  #pragma unroll
  for (int r = 0; r < 4; ++r) rinv[r] = 1.0f / sum[r];

  // ---- pass 2: recompute e, vc GEMM, normalize, transposed store ----
  float* outp = out + (size_t)bh * 1024 * 1024;
  const short* Vh = Vm + h * 1024 * KP;
  for (int dc = 0; dc < 16; ++dc){
    __syncthreads();
    #pragma unroll
    for (int it = 0; it < 3; ++it){
      int idx = it * 256 + t;
      int row = idx / 12, seg = idx - row * 12;
      *(uint4*)(&Bst[row * LSTR + seg * 8]) =
          *(const uint4*)(Bb + (dc * 64 + row) * KP + seg * 8);
      *(uint4*)(&Vst[row * LSTR + seg * 8]) =
          *(const uint4*)(Vh + (dc * 64 + row) * KP + seg * 8);
    }
    __syncthreads();
    #pragma unroll
    for (int sd = 0; sd < 4; ++sd){
      f32x4 e  = {0.f, 0.f, 0.f, 0.f};
      f32x4 vv = {0.f, 0.f, 0.f, 0.f};
      #pragma unroll
      for (int s = 0; s < 3; ++s){
        short8 bf = *(const short8*)(&Bst[(sd * 16 + ln) * LSTR + s * 32 + q * 8]);
        short8 vf = *(const short8*)(&Vst[(sd * 16 + ln) * LSTR + s * 32 + q * 8]);
        e  = __builtin_amdgcn_mfma_f32_16x16x32_bf16(af[s], bf, e, 0, 0, 0);
        vv = __builtin_amdgcn_mfma_f32_16x16x32_bf16(bn[s], vf, vv, 0, 0, 0);
      }
      f32x4 o;
      #pragma unroll
      for (int r = 0; r < 4; ++r)
        o[r] = __builtin_amdgcn_exp2f(e[r] * KEXP) * rinv[r] * vv[r];
      // out[((b*8+h)*1024 + d)*1024 + n], 4 consecutive n per lane
      *(f32x4*)(outp + (dc * 64 + sd * 16 + ln) * NN + n0 + w * 16 + q * 4) = o;
    }
  }
}

extern "C" void kernel_launch(void* const* d_in, const int* in_sizes, int n_in,
                              void* d_out, int out_size, void* d_ws, size_t ws_size,
                              hipStream_t stream){
  const float* coord = (const float*)d_in[0];
  const float* x     = (const float*)d_in[1];
  const float* nbr   = (const float*)d_in[2];
  const float* Wq    = (const float*)d_in[3];
  const float* Wk    = (const float*)d_in[4];
  const float* Wv    = (const float*)d_in[5];
  const float* Wlq   = (const float*)d_in[6];
  const float* blq   = (const float*)d_in[7];
  const float* Wlv   = (const float*)d_in[8];
  const float* blv   = (const float*)d_in[9];
  float* out = (float*)d_out;

  char* ws = (char*)d_ws;
  short* PT = (short*)ws;                         // 8*96*64*2   =   98304 B
  short* Bm = (short*)(ws + 98304);               // 4*1024*96*2 =  786432 B
  short* Vm = (short*)(ws + 98304 + 786432);      // 8*1024*96*2 = 1572864 B
  // total ws: 2,457,600 B

  k_prep_pt<<<dim3(12, 8), 1024, 0, stream>>>(Wq, Wk, Wlq, blq, PT);
  k_prep_b <<<dim3(16, 4),  256, 0, stream>>>(nbr, coord, Bm);
  k_prep_v <<<128,          256, 0, stream>>>(Wv, Wlv, blv, Vm);
  attn_main<<<512,          256, 0, stream>>>(x, PT, Bm, Vm, out);
}

// Round 2
// 248.859 us; speedup vs baseline: 1.0140x; 1.0140x over previous
//
#include <hip/hip_runtime.h>

// Dims (fixed by the reference)
#define NN 1024
// K padded: 64 (ns) + 3 (coords) + 1 (bias) = 68 -> pad to 96 = 3 x 32
#define KP 96
#define LSTR 104   // LDS row stride in shorts (208 B; dword stride 52 -> 2-way banks, free)

typedef __attribute__((ext_vector_type(8))) short short8;
typedef __attribute__((ext_vector_type(4))) short short4v;
typedef __attribute__((ext_vector_type(4))) float f32x4;

__device__ __forceinline__ short f2bf(float f){
  unsigned u = __builtin_bit_cast(unsigned, f);
  u += 0x7FFFu + ((u >> 16) & 1u);       // RNE
  return (short)(u >> 16);
}

// ---------------- K1: per-head Gram panel (fp32, d-split + atomics) --------
// PTf[h][kk][c] = sum_d Wq[h*1024+d][c] * X[d][kk]
// X[d][kk] = Wk[.,kk] (kk<64) | Wlq[.,kk-64] (64..66) | blq (67) | 0 (pad)
__global__ __launch_bounds__(1024) void k_prep_pt(
    const float* __restrict__ Wq, const float* __restrict__ Wk,
    const float* __restrict__ Wlq, const float* __restrict__ blq,
    float* __restrict__ PTf){
  int t = threadIdx.x, c = t & 63, p = t >> 6;          // p: 0..15 d-partitions
  int h = blockIdx.y, kk0 = blockIdx.x * 8, dz = blockIdx.z;  // dz: 0..3
  float acc[8];
  #pragma unroll
  for (int i = 0; i < 8; ++i) acc[i] = 0.f;
  #pragma unroll
  for (int i = 0; i < 16; ++i){
    int o = h * 1024 + p * 64 + dz * 16 + i;
    float wq = Wq[o * 64 + c];                           // coalesced over c
    #pragma unroll
    for (int j = 0; j < 8; ++j){
      int kk = kk0 + j;
      float bv;
      if (kk < 64)        bv = Wk[o * 64 + kk];
      else if (kk < 67)   bv = Wlq[o * 3 + (kk - 64)];
      else if (kk == 67)  bv = blq[o];
      else                bv = 0.f;
      acc[j] += wq * bv;
    }
  }
  __shared__ float red[16][64][8];
  #pragma unroll
  for (int j = 0; j < 8; ++j) red[p][c][j] = acc[j];
  __syncthreads();
  if (p == 0){
    #pragma unroll
    for (int j = 0; j < 8; ++j){
      float s = 0.f;
      for (int pp = 0; pp < 16; ++pp) s += red[pp][c][j];
      atomicAdd(&PTf[(h * KP + kk0 + j) * 64 + c], s);
    }
  }
}

// ---------------- K2: B panel  Bmat[b][m][kk] (bf16) ----------------
__global__ __launch_bounds__(256) void k_prep_b(
    const float* __restrict__ ns, const float* __restrict__ coord,
    short* __restrict__ Bm){
  int t = threadIdx.x;
  int b = blockIdx.y, m0 = blockIdx.x * 64;
  __shared__ float nsT[64][65];
  __shared__ float cst[3][64];
  #pragma unroll
  for (int it = 0; it < 16; ++it){
    int idx = it * 256 + t;
    int c = idx >> 6, mm = idx & 63;
    nsT[mm][c] = ns[(b * 64 + c) * NN + m0 + mm];        // coalesced over mm
  }
  if (t < 192){
    int j = t >> 6, mm = t & 63;
    cst[j][mm] = coord[(b * 3 + j) * NN + m0 + mm];
  }
  __syncthreads();
  #pragma unroll
  for (int it = 0; it < 24; ++it){
    int idx = it * 256 + t;                              // 64*96 = 6144
    int mm = idx / KP, kk = idx - mm * KP;
    float v = (kk < 64) ? nsT[mm][kk]
            : (kk < 67) ? cst[kk - 64][mm]
            : (kk == 67) ? 1.f : 0.f;
    Bm[(b * NN + m0 + mm) * KP + kk] = f2bf(v);
  }
}

// ---------------- K3: V panel  Vm[h*1024+d][kk] (bf16) ----------------
__global__ __launch_bounds__(256) void k_prep_v(
    const float* __restrict__ Wv, const float* __restrict__ Wlv,
    const float* __restrict__ blv, short* __restrict__ Vm){
  int t = threadIdx.x, o0 = blockIdx.x * 64;
  #pragma unroll
  for (int it = 0; it < 24; ++it){
    int idx = it * 256 + t;
    int r = idx / KP, kk = idx - r * KP;
    int o = o0 + r;
    float v = (kk < 64) ? Wv[o * 64 + kk]
            : (kk < 67) ? Wlv[o * 3 + (kk - 64)]
            : (kk == 67) ? blv[o] : 0.f;
    Vm[o * KP + kk] = f2bf(v);
  }
}

// ---------------- K4: fused attention (barrier-free main loops) ------------
// Per WG: (b,h, 64-row n-block). Each wave owns an m/d QUARTER (256 of 1024)
// and computes for ALL 64 n-rows (4 row fragments af/bn held in registers).
// Pass1: partial row sums over wave's m-quarter; one LDS reduce across waves.
// Pass2: wave's d-quarter: recompute e + vc GEMM, normalize, f32x4 store.
__global__ __launch_bounds__(256) void attn_main(
    const float* __restrict__ xs, const float* __restrict__ PTf,
    const short* __restrict__ Bmat, const short* __restrict__ Vm,
    float* __restrict__ out){
  __shared__ short xsL[64 * 64];        // bf16 [c][n_local]  (8 KB)
  __shared__ short AL[64 * LSTR];       // bf16 A rows [n_local][kk] (13.3 KB)
  __shared__ float redS[64 * 4];        // per-row partial sums x 4 waves
  const int t = threadIdx.x, w = t >> 6, lane = t & 63;
  const int q = lane >> 4, ln = lane & 15;
  const int blk = blockIdx.x, nb = blk & 15, bh = blk >> 4;
  const int b = bh >> 3, h = bh & 7;
  const int n0 = nb * 64;

  // ---- stage xs[b][0..63][n0..n0+63] as bf16 ----
  const float* xsb = xs + b * 64 * NN;
  #pragma unroll
  for (int it = 0; it < 4; ++it){
    int idx = it * 256 + t;                     // 1024 float4 units
    int c = idx >> 4, nn4 = (idx & 15) << 2;
    f32x4 v = *(const f32x4*)(xsb + c * NN + n0 + nn4);
    short4v pk;
    #pragma unroll
    for (int j = 0; j < 4; ++j) pk[j] = f2bf(v[j]);
    *(short4v*)(&xsL[c * 64 + nn4]) = pk;
  }
  __syncthreads();

  // ---- build A rows w*16..w*16+15 via MFMA: A = xs^T . PT^T ----
  short8 xf0, xf1;
  #pragma unroll
  for (int j = 0; j < 8; ++j){
    xf0[j] = xsL[(q * 8 + j) * 64 + w * 16 + ln];
    xf1[j] = xsL[(32 + q * 8 + j) * 64 + w * 16 + ln];
  }
  const float* PTh = PTf + h * KP * 64;
  #pragma unroll
  for (int kt = 0; kt < 6; ++kt){
    const float* pr = PTh + (kt * 16 + ln) * 64;
    f32x4 pa = *(const f32x4*)(pr + q * 8);
    f32x4 pb = *(const f32x4*)(pr + q * 8 + 4);
    f32x4 pc = *(const f32x4*)(pr + 32 + q * 8);
    f32x4 pd = *(const f32x4*)(pr + 32 + q * 8 + 4);
    short8 p0, p1;
    #pragma unroll
    for (int j = 0; j < 4; ++j){
      p0[j] = f2bf(pa[j]); p0[4 + j] = f2bf(pb[j]);
      p1[j] = f2bf(pc[j]); p1[4 + j] = f2bf(pd[j]);
    }
    f32x4 a = {0.f, 0.f, 0.f, 0.f};
    a = __builtin_amdgcn_mfma_f32_16x16x32_bf16(xf0, p0, a, 0, 0, 0);
    a = __builtin_amdgcn_mfma_f32_16x16x32_bf16(xf1, p1, a, 0, 0, 0);
    #pragma unroll
    for (int r = 0; r < 4; ++r)
      AL[(w * 16 + q * 4 + r) * LSTR + kt * 16 + ln] = f2bf(a[r]);
  }
  __syncthreads();

  // ---- persistent fragments: all 64 rows ----
  short8 af[4][3], bn[4][3];
  const short* Bb = Bmat + b * NN * KP;
  #pragma unroll
  for (int rf = 0; rf < 4; ++rf){
    #pragma unroll
    for (int s = 0; s < 3; ++s){
      af[rf][s] = *(const short8*)(&AL[(rf * 16 + ln) * LSTR + s * 32 + q * 8]);
      bn[rf][s] = *(const short8*)(Bb + (n0 + rf * 16 + ln) * KP + s * 32 + q * 8);
    }
  }
  const float KEXP = 0.045084220f;   // log2(e)/32  (SCALE = sqrt(1024) = 32)

  // ---- pass 1: partial row sums over wave's m-quarter (no barriers) ----
  float sum[4][4];
  #pragma unroll
  for (int rf = 0; rf < 4; ++rf)
    #pragma unroll
    for (int r = 0; r < 4; ++r) sum[rf][r] = 0.f;

  short8 bf0, bf1, bf2;
  {
    const short* bp = Bb + (w * 256 + ln) * KP + q * 8;
    bf0 = *(const short8*)(bp);
    bf1 = *(const short8*)(bp + 32);
    bf2 = *(const short8*)(bp + 64);
  }
  for (int ms = 0; ms < 16; ++ms){
    short8 nb0, nb1, nb2;
    {
      int msn = (ms + 1) & 15;
      const short* bp = Bb + (w * 256 + msn * 16 + ln) * KP + q * 8;
      nb0 = *(const short8*)(bp);
      nb1 = *(const short8*)(bp + 32);
      nb2 = *(const short8*)(bp + 64);
    }
    #pragma unroll
    for (int rf = 0; rf < 4; ++rf){
      f32x4 e = {0.f, 0.f, 0.f, 0.f};
      e = __builtin_amdgcn_mfma_f32_16x16x32_bf16(af[rf][0], bf0, e, 0, 0, 0);
      e = __builtin_amdgcn_mfma_f32_16x16x32_bf16(af[rf][1], bf1, e, 0, 0, 0);
      e = __builtin_amdgcn_mfma_f32_16x16x32_bf16(af[rf][2], bf2, e, 0, 0, 0);
      #pragma unroll
      for (int r = 0; r < 4; ++r)
        sum[rf][r] += __builtin_amdgcn_exp2f(e[r] * KEXP);
    }
    bf0 = nb0; bf1 = nb1; bf2 = nb2;
  }
  // reduce over the 16 m-columns (ln bits), then across waves via LDS
  #pragma unroll
  for (int rf = 0; rf < 4; ++rf){
    #pragma unroll
    for (int r = 0; r < 4; ++r){
      float s = sum[rf][r];
      s += __shfl_xor(s, 1); s += __shfl_xor(s, 2);
      s += __shfl_xor(s, 4); s += __shfl_xor(s, 8);
      sum[rf][r] = s;
    }
  }
  if (ln == 0){
    #pragma unroll
    for (int rf = 0; rf < 4; ++rf)
      #pragma unroll
      for (int r = 0; r < 4; ++r)
        redS[(rf * 16 + q * 4 + r) * 4 + w] = sum[rf][r];
  }
  __syncthreads();
  float rinv[4][4];
  #pragma unroll
  for (int rf = 0; rf < 4; ++rf){
    #pragma unroll
    for (int r = 0; r < 4; ++r){
      f32x4 v4 = *(const f32x4*)(&redS[(rf * 16 + q * 4 + r) * 4]);
      rinv[rf][r] = 1.0f / (v4[0] + v4[1] + v4[2] + v4[3]);
    }
  }

  // ---- pass 2: wave's d-quarter, recompute e + vc GEMM, store -----------
  float* outp = out + (size_t)bh * (1024 * 1024);
  const short* Vh = Vm + h * 1024 * KP;
  short8 vf0, vf1, vf2;
  {
    const short* bp = Bb + (w * 256 + ln) * KP + q * 8;
    const short* vp = Vh + (w * 256 + ln) * KP + q * 8;
    bf0 = *(const short8*)(bp); bf1 = *(const short8*)(bp + 32); bf2 = *(const short8*)(bp + 64);
    vf0 = *(const short8*)(vp); vf1 = *(const short8*)(vp + 32); vf2 = *(const short8*)(vp + 64);
  }
  for (int ds = 0; ds < 16; ++ds){
    int d0 = w * 256 + ds * 16;
    short8 nb0, nb1, nb2, nv0, nv1, nv2;
    {
      int dsn = (ds + 1) & 15;
      const short* bp = Bb + (w * 256 + dsn * 16 + ln) * KP + q * 8;
      const short* vp = Vh + (w * 256 + dsn * 16 + ln) * KP + q * 8;
      nb0 = *(const short8*)(bp); nb1 = *(const short8*)(bp + 32); nb2 = *(const short8*)(bp + 64);
      nv0 = *(const short8*)(vp); nv1 = *(const short8*)(vp + 32); nv2 = *(const short8*)(vp + 64);
    }
    #pragma unroll
    for (int rf = 0; rf < 4; ++rf){
      f32x4 e  = {0.f, 0.f, 0.f, 0.f};
      f32x4 vv = {0.f, 0.f, 0.f, 0.f};
      e  = __builtin_amdgcn_mfma_f32_16x16x32_bf16(af[rf][0], bf0, e, 0, 0, 0);
      e  = __builtin_amdgcn_mfma_f32_16x16x32_bf16(af[rf][1], bf1, e, 0, 0, 0);
      e  = __builtin_amdgcn_mfma_f32_16x16x32_bf16(af[rf][2], bf2, e, 0, 0, 0);
      vv = __builtin_amdgcn_mfma_f32_16x16x32_bf16(bn[rf][0], vf0, vv, 0, 0, 0);
      vv = __builtin_amdgcn_mfma_f32_16x16x32_bf16(bn[rf][1], vf1, vv, 0, 0, 0);
      vv = __builtin_amdgcn_mfma_f32_16x16x32_bf16(bn[rf][2], vf2, vv, 0, 0, 0);
      f32x4 o;
      #pragma unroll
      for (int r = 0; r < 4; ++r)
        o[r] = __builtin_amdgcn_exp2f(e[r] * KEXP) * rinv[rf][r] * vv[r];
      // out[((b*8+h)*1024 + d)*1024 + n]; lane writes rows d0+ln, cols n0+rf*16+q*4..+3
      *(f32x4*)(outp + (d0 + ln) * NN + n0 + rf * 16 + q * 4) = o;
    }
    bf0 = nb0; bf1 = nb1; bf2 = nb2;
    vf0 = nv0; vf1 = nv1; vf2 = nv2;
  }
}

extern "C" void kernel_launch(void* const* d_in, const int* in_sizes, int n_in,
                              void* d_out, int out_size, void* d_ws, size_t ws_size,
                              hipStream_t stream){
  const float* coord = (const float*)d_in[0];
  const float* x     = (const float*)d_in[1];
  const float* nbr   = (const float*)d_in[2];
  const float* Wq    = (const float*)d_in[3];
  const float* Wk    = (const float*)d_in[4];
  const float* Wv    = (const float*)d_in[5];
  const float* Wlq   = (const float*)d_in[6];
  const float* blq   = (const float*)d_in[7];
  const float* Wlv   = (const float*)d_in[8];
  const float* blv   = (const float*)d_in[9];
  float* out = (float*)d_out;

  char* ws = (char*)d_ws;
  float* PTf = (float*)ws;                        // 8*96*64*4   =  196608 B
  short* Bm  = (short*)(ws + 196608);             // 4*1024*96*2 =  786432 B
  short* Vm  = (short*)(ws + 196608 + 786432);    // 8*1024*96*2 = 1572864 B
  // total ws: 2,555,904 B

  hipMemsetAsync(PTf, 0, 196608, stream);
  k_prep_pt<<<dim3(12, 8, 4), 1024, 0, stream>>>(Wq, Wk, Wlq, blq, PTf);
  k_prep_b <<<dim3(16, 4),     256, 0, stream>>>(nbr, coord, Bm);
  k_prep_v <<<128,             256, 0, stream>>>(Wv, Wlv, blv, Vm);
  attn_main<<<512,             256, 0, stream>>>(x, PTf, Bm, Vm, out);
}